// Round 3
// baseline (25658.105 us; speedup 1.0000x reference)
//
#include <hip/hip_runtime.h>
#include <cmath>

#define B 128
#define L 64
#define D 512
#define H 256
#define G4 1024
#define TOTROWS 2080   // 64*65/2

__device__ __forceinline__ float sigf(float x) { return 1.0f / (1.0f + expf(-x)); }

// ---------------- init: uh0 = unit_hidden * existence -> units chunk (len=64); ex init ----
// existence arrives as int32 (harness normalizes bool -> int32)
__global__ __launch_bounds__(256) void k_init(const int* __restrict__ ex_in,
                                              const float* __restrict__ uh_in,
                                              float* __restrict__ units,
                                              float* __restrict__ exdst) {
    int idx = blockIdx.x * 256 + threadIdx.x;   // over B*L*(D/4) = 1,048,576
    int bt = idx >> 7;
    int r  = idx & 127;
    float m = (ex_in[bt] != 0) ? 1.0f : 0.0f;
    const float4* src = (const float4*)uh_in;
    float4 v = src[idx];
    v.x *= m; v.y *= m; v.z *= m; v.w *= m;
    int b = bt >> 6, t = bt & 63;
    float4* dst = (float4*)units;
    dst[((size_t)b * TOTROWS + 2016 + t) * 128 + r] = v;
    if (r == 0) exdst[bt] = m;
}

// ---------------- one-time: W_ih transposed to [d][k][1024] ----------------
__global__ __launch_bounds__(256) void k_wprep_ih(const float* __restrict__ wf,
                                                  const float* __restrict__ wb,
                                                  float* __restrict__ wt) {
    int o = blockIdx.x * 256 + threadIdx.x;   // 2*512*1024 = 1,048,576
    int n = o & 1023;
    int k = (o >> 10) & 511;
    int d = o >> 19;
    const float* W = d ? wb : wf;
    wt[o] = W[n * 512 + k];
}

// ---------------- one-time: W_hh into per-lane register layout -------------
// wt[((d*16+jg)*256 + lane)*64 + q*16 + i4*4 + c] = W[d][q*256 + jg*16 + jj][kseg*16 + i4*4 + c]
// lane = kseg*16 + jj
__global__ __launch_bounds__(256) void k_wprep_hh(const float* __restrict__ wf,
                                                  const float* __restrict__ wb,
                                                  float* __restrict__ wt) {
    int o = blockIdx.x * 256 + threadIdx.x;   // 2*16*256*64 = 524,288
    int c    = o & 3;
    int i4   = (o >> 2) & 3;
    int q    = (o >> 4) & 3;
    int lane = (o >> 6) & 255;
    int jg   = (o >> 14) & 15;
    int d    = o >> 18;
    int jj = lane & 15, kseg = lane >> 4;
    const float* W = d ? wb : wf;
    wt[o] = W[(q * 256 + jg * 16 + jj) * 256 + kseg * 16 + i4 * 4 + c];
}

// ---------------- per-iteration fresh xg = uh @ W_ih^T (f32) ----------------
// grid: (16 n-tiles of 128 over N=2048, ceil(B*len/128)), 256 threads, tile 128x128, 8x8 frag
__global__ __launch_bounds__(256) void k_xg(const float* __restrict__ units,
                                            const float* __restrict__ wihT,
                                            float* __restrict__ xg, int len, int offL) {
    __shared__ __align__(16) float As[32 * 132];
    __shared__ __align__(16) float Bs[32 * 132];
    int tid = threadIdx.x;
    int nt = blockIdx.x, mtb = blockIdx.y;
    int d = nt >> 3;
    int gbase = (nt & 7) * 128;
    int M = 128 * len;

    int arow = tid & 127, ahalf = tid >> 7;
    int agm = mtb * 128 + arow;
    const float* aptr = nullptr;
    if (agm < M) {
        int ab = agm / len, at = agm - ab * len;
        aptr = units + ((size_t)ab * TOTROWS + offL + at) * 512;
    }
    int bcol = (tid & 31) * 4, bkr = tid >> 5;
    int tm = tid >> 4, tn = tid & 15;

    float acc[8][8];
#pragma unroll
    for (int i = 0; i < 8; i++)
#pragma unroll
        for (int j = 0; j < 8; j++) acc[i][j] = 0.f;

    for (int k0 = 0; k0 < 512; k0 += 32) {
#pragma unroll
        for (int i4 = 0; i4 < 4; i4++) {
            float4 v;
            if (aptr) v = *(const float4*)&aptr[k0 + ahalf * 16 + i4 * 4];
            else { v.x = v.y = v.z = v.w = 0.f; }
            int kk = ahalf * 16 + i4 * 4;
            As[(kk + 0) * 132 + arow] = v.x;
            As[(kk + 1) * 132 + arow] = v.y;
            As[(kk + 2) * 132 + arow] = v.z;
            As[(kk + 3) * 132 + arow] = v.w;
        }
#pragma unroll
        for (int i = 0; i < 4; i++) {
            int kk = bkr * 4 + i;
            float4 v = *(const float4*)&wihT[((size_t)(d * 512 + k0 + kk)) * 1024 + gbase + bcol];
            *(float4*)&Bs[kk * 132 + bcol] = v;
        }
        __syncthreads();
#pragma unroll 4
        for (int k = 0; k < 32; k++) {
            float4 a0 = *(const float4*)&As[k * 132 + tm * 8];
            float4 a1 = *(const float4*)&As[k * 132 + tm * 8 + 4];
            float4 b0 = *(const float4*)&Bs[k * 132 + tn * 8];
            float4 b1 = *(const float4*)&Bs[k * 132 + tn * 8 + 4];
            float av[8] = {a0.x, a0.y, a0.z, a0.w, a1.x, a1.y, a1.z, a1.w};
            float bv[8] = {b0.x, b0.y, b0.z, b0.w, b1.x, b1.y, b1.z, b1.w};
#pragma unroll
            for (int i = 0; i < 8; i++)
#pragma unroll
                for (int j = 0; j < 8; j++) acc[i][j] = fmaf(av[i], bv[j], acc[i][j]);
        }
        __syncthreads();
    }
#pragma unroll
    for (int i = 0; i < 8; i++) {
        int gm = mtb * 128 + tm * 8 + i;
        if (gm < M) {
            int bb = gm / len, tt = gm - bb * len;
            float* Cp = xg + ((size_t)(d * B + bb) * L + tt) * G4 + gbase + tn * 8;
            float4 v0; v0.x = acc[i][0]; v0.y = acc[i][1]; v0.z = acc[i][2]; v0.w = acc[i][3];
            float4 v1; v1.x = acc[i][4]; v1.y = acc[i][5]; v1.z = acc[i][6]; v1.w = acc[i][7];
            *(float4*)&Cp[0] = v0;
            *(float4*)&Cp[4] = v1;
        }
    }
}

// ---------------- one LSTM timestep, both directions ----------------
// grid: (16 j-groups, 8 b-groups, 2 dirs), 256 threads. W_hh in registers (64 VGPR/lane).
__global__ __launch_bounds__(256) void k_step(const float* __restrict__ xg,
        const float* __restrict__ wtHH,
        const float* __restrict__ bias_f, const float* __restrict__ bias_b,
        const float* __restrict__ ow, const float* __restrict__ h0, const float* __restrict__ c0,
        const float* __restrict__ h_rd, float* __restrict__ h_wr,
        const float* __restrict__ c_rd, float* __restrict__ c_wr,
        double* __restrict__ o_part, int s, int len) {
    __shared__ __align__(16) float hs[256 * 16];     // [k][16 b, xor-swizzled float4 groups] 16KB
    __shared__ __align__(16) float pb[8 * 16 * 68];  // [slice][jj][64+pad] 34.8KB
    int tid = threadIdx.x;
    int jg = blockIdx.x, sg = blockIdx.y, d = blockIdx.z;
    int t = d ? (len - 1 - s) : s;
    int b0 = sg * 16, j0 = jg * 16;

    float4 wreg[16];
    {
        const float4* wp = (const float4*)(wtHH + ((size_t)(d * 16 + jg) * 256 + tid) * 64);
#pragma unroll
        for (int m = 0; m < 16; m++) wreg[m] = wp[m];
    }
    {
        int b = tid & 15, kc = tid >> 4;
        int bq = b >> 2, br = b & 3;
        int swz = ((bq ^ (kc & 3)) << 2) + br;
        const float* hsrc = (s == 0) ? (h0 + d * H)
                                     : (h_rd + ((size_t)(d * B + b0 + b)) * H);
#pragma unroll
        for (int i4 = 0; i4 < 4; i4++) {
            float4 v = *(const float4*)&hsrc[kc * 16 + i4 * 4];
            int kk = kc * 16 + i4 * 4;
            hs[(kk + 0) * 16 + swz] = v.x;
            hs[(kk + 1) * 16 + swz] = v.y;
            hs[(kk + 2) * 16 + swz] = v.z;
            hs[(kk + 3) * 16 + swz] = v.w;
        }
    }
    __syncthreads();
    {
        int jj = tid & 15, kseg = tid >> 4;
        int ks3 = kseg & 3;
        float acc[4][16];
#pragma unroll
        for (int q = 0; q < 4; q++)
#pragma unroll
            for (int u = 0; u < 16; u++) acc[q][u] = 0.f;
#pragma unroll
        for (int i4 = 0; i4 < 4; i4++) {
#pragma unroll
            for (int c = 0; c < 4; c++) {
                int k = (kseg << 4) + (i4 << 2) + c;
                const float* hb = &hs[k << 4];
                float4 hv[4];
#pragma unroll
                for (int bq = 0; bq < 4; bq++)
                    hv[bq] = *(const float4*)&hb[((bq ^ ks3) << 2)];
#pragma unroll
                for (int q = 0; q < 4; q++) {
                    float4 wv = wreg[q * 4 + i4];
                    float w = (c == 0) ? wv.x : (c == 1) ? wv.y : (c == 2) ? wv.z : wv.w;
#pragma unroll
                    for (int bq = 0; bq < 4; bq++) {
                        acc[q][bq * 4 + 0] = fmaf(hv[bq].x, w, acc[q][bq * 4 + 0]);
                        acc[q][bq * 4 + 1] = fmaf(hv[bq].y, w, acc[q][bq * 4 + 1]);
                        acc[q][bq * 4 + 2] = fmaf(hv[bq].z, w, acc[q][bq * 4 + 2]);
                        acc[q][bq * 4 + 3] = fmaf(hv[bq].w, w, acc[q][bq * 4 + 3]);
                    }
                }
            }
        }
#pragma unroll
        for (int q = 0; q < 4; q++)
#pragma unroll
            for (int u = 0; u < 16; u++) acc[q][u] += __shfl_xor(acc[q][u], 32);
        if (!(tid & 32)) {
            int slice = ((tid >> 6) << 1) | ((tid >> 4) & 1);
            float* pbp = &pb[(slice * 16 + jj) * 68];
#pragma unroll
            for (int bb = 0; bb < 16; bb++) {
                float4 v; v.x = acc[0][bb]; v.y = acc[1][bb]; v.z = acc[2][bb]; v.w = acc[3][bb];
                *(float4*)&pbp[bb * 4] = v;
            }
        }
    }
    __syncthreads();
    {
        int bF = tid >> 4, jjF = tid & 15;
        int b = b0 + bF, j = j0 + jjF;
        float g4[4] = {0.f, 0.f, 0.f, 0.f};
#pragma unroll
        for (int sl = 0; sl < 8; sl++) {
            float4 pv = *(const float4*)&pb[(sl * 16 + jjF) * 68 + bF * 4];
            g4[0] += pv.x; g4[1] += pv.y; g4[2] += pv.z; g4[3] += pv.w;
        }
        const float* biasp = d ? bias_b : bias_f;
        size_t xgo = (((size_t)(d * B + b)) * L + t) * G4 + j;
        float g[4];
#pragma unroll
        for (int q = 0; q < 4; q++) {
            float xt = xg[xgo + q * 256] + biasp[q * 256 + j];
            g[q] = xt + g4[q];
        }
        float c_old = (s == 0) ? c0[d * H + j] : c_rd[((size_t)(d * B + b)) * H + j];
        float ig = sigf(g[0]);
        float fg = sigf(g[1]);
        float gg = tanhf(g[2]);
        float og = sigf(g[3]);
        float c = fg * c_old + ig * gg;
        float h = og * tanhf(c);
        c_wr[((size_t)(d * B + b)) * H + j] = c;
        h_wr[((size_t)(d * B + b)) * H + j] = h;
        double contrib = (double)h * (double)ow[d * H + j];
#pragma unroll
        for (int off = 8; off > 0; off >>= 1) contrib += __shfl_xor(contrib, off, 16);
        if (jjF == 0) o_part[(((size_t)(d * 16 + jg)) * B + b) * L + t] = contrib;
    }
}

// ---------------- orient finalize + write orients/exs chunks ----------------
__global__ void k_orient(const double* __restrict__ o_part, const float* __restrict__ ob,
                         const float* __restrict__ exsrc, float* __restrict__ o_buf,
                         float* __restrict__ out_or, float* __restrict__ out_ex,
                         int len, int offL) {
    int b = blockIdx.x, t = threadIdx.x;
    if (t >= len) return;
    double sum = (double)ob[0];
#pragma unroll 4
    for (int i = 0; i < 32; i++) sum += o_part[((size_t)i * B + b) * L + t];
    float o = (float)sum;
    o_buf[b * L + t] = o;
    out_or[(size_t)b * TOTROWS + offL + t] = o;
    out_ex[(size_t)b * TOTROWS + offL + t] = exsrc[b * L + t];
}

// ---------------- advance: merge units chunk + ex ping-pong ----
// grid: (2, 128)
__global__ __launch_bounds__(256) void k_advance(const float* __restrict__ o_buf,
        const float* __restrict__ exsrc, float* __restrict__ exdst,
        float* __restrict__ units, int len, int offL) {
    int bx = blockIdx.x, b = blockIdx.y, tid = threadIdx.x;
    __shared__ float lwa[64], rwa[64];
    int n = len - 1;
    if (tid < n) {
        float ot = o_buf[b * L + tid], on = o_buf[b * L + tid + 1];
        float ext = exsrc[b * L + tid], exn = exsrc[b * L + tid + 1];
        float lw = (ot > 0.f && ext != 0.f) ? 1.f : 0.f;
        float rw = (!(on > 0.f) && exn != 0.f) ? 1.f : 0.f;
        lwa[tid] = lw; rwa[tid] = rw;
        if (bx == 0) exdst[b * L + tid] = ((lw + rw) > 0.f) ? 1.f : 0.f;
    }
    __syncthreads();
    int k = bx * 256 + tid;
    const float* src = units + ((size_t)b * TOTROWS + offL) * D + k;
    float* dst = units + ((size_t)b * TOTROWS + (offL - n)) * D + k;
    for (int t = 0; t < n; ++t)
        dst[(size_t)t * D] = lwa[t] * src[(size_t)t * D] + rwa[t] * src[(size_t)(t + 1) * D];
}

extern "C" void kernel_launch(void* const* d_in, const int* in_sizes, int n_in,
                              void* d_out, int out_size, void* d_ws, size_t ws_size,
                              hipStream_t stream) {
    const int*   ex_in   = (const int*)d_in[0];
    const float* uh_in   = (const float*)d_in[1];
    const float* w_ih_f  = (const float*)d_in[2];
    const float* w_hh_f  = (const float*)d_in[3];
    const float* b_f     = (const float*)d_in[4];
    const float* w_ih_b  = (const float*)d_in[5];
    const float* w_hh_b  = (const float*)d_in[6];
    const float* b_b     = (const float*)d_in[7];
    const float* orientw = (const float*)d_in[8];
    const float* orientb = (const float*)d_in[9];
    const float* h0      = (const float*)d_in[10];
    const float* c0      = (const float*)d_in[11];

    float* units  = (float*)d_out;
    float* out_or = units + (size_t)B * TOTROWS * D;
    float* out_ex = out_or + (size_t)B * TOTROWS;

    float* xg    = (float*)d_ws;                       // 2*B*L*G4 = 16,777,216 f
    float* wihT  = xg + (size_t)2 * B * L * G4;        // 1,048,576 f
    float* wtHH  = wihT + (size_t)2 * 512 * 1024;      // 524,288 f
    float* hbuf  = wtHH + (size_t)524288;              // 2 * (2*B*H) = 131,072 f
    float* cbuf  = hbuf + 2 * (2 * B * H);             // 131,072 f
    float* obuf  = cbuf + 2 * (2 * B * H);             // 8,192 f
    float* exb0  = obuf + B * L;                       // 8,192 f
    float* exb1  = exb0 + B * L;                       // 8,192 f
    double* opart = (double*)(exb1 + B * L);           // 32*B*L doubles = 2MB

    k_init<<<4096, 256, 0, stream>>>(ex_in, uh_in, units, exb0);
    k_wprep_ih<<<4096, 256, 0, stream>>>(w_ih_f, w_ih_b, wihT);
    k_wprep_hh<<<2048, 256, 0, stream>>>(w_hh_f, w_hh_b, wtHH);

    for (int it = 0; it < 64; ++it) {
        int len = 64 - it;
        int offL = len * (len - 1) / 2;
        float* exs = (it & 1) ? exb1 : exb0;
        float* exd = (it & 1) ? exb0 : exb1;
        int mt = (B * len + 127) / 128;
        k_xg<<<dim3(16, mt), 256, 0, stream>>>(units, wihT, xg, len, offL);
        for (int s = 0; s < len; ++s) {
            int p = s & 1;
            const float* h_rd = hbuf + (size_t)p * (2 * B * H);
            float*       h_wr = hbuf + (size_t)(p ^ 1) * (2 * B * H);
            const float* c_rd = cbuf + (size_t)p * (2 * B * H);
            float*       c_wr = cbuf + (size_t)(p ^ 1) * (2 * B * H);
            k_step<<<dim3(16, 8, 2), 256, 0, stream>>>(xg, wtHH, b_f, b_b,
                    orientw, h0, c0, h_rd, h_wr, c_rd, c_wr, opart, s, len);
        }
        k_orient<<<128, 64, 0, stream>>>(opart, orientb, exs, obuf, out_or, out_ex, len, offL);
        if (len > 1)
            k_advance<<<dim3(2, 128), 256, 0, stream>>>(obuf, exs, exd, units, len, offL);
    }
    (void)in_sizes; (void)n_in; (void)out_size; (void)ws_size;
}